// Round 6
// baseline (8213.253 us; speedup 1.0000x reference)
//
#include <hip/hip_runtime.h>
#include <hip/hip_bf16.h>

// ---------------------------------------------------------------------------
// CompositePulseTransformerDecoder — MI355X (gfx950), round 6
// KV-cached incremental decode + cross-attn collapsed to constant.
// 32 blocks = 8 chains x 4 slices, 512 threads (8 waves) each.
// Two flag syncs per layer (A: qkv/attn/Wo-partial, B: lin1/lin2-partial).
// NEW: fence-free sync — exchange data moves via agent-scope RELAXED atomics
// (write-through / L2-bypass), flags relaxed; NO release wbl2, NO acquire
// buffer_inv. KV cache + cc stay L2-resident the whole run.
// ---------------------------------------------------------------------------

typedef __attribute__((ext_vector_type(8))) short short8;
typedef __attribute__((ext_vector_type(4))) float f32x4;

#define EPS_ 1e-5f

__device__ __forceinline__ unsigned short f2b(float x){
  union { float f; unsigned u; } c; c.f = x;
  unsigned r = (c.u + 0x7fffu + ((c.u >> 16) & 1u)) >> 16;
  return (unsigned short)r;
}
__device__ __forceinline__ float b2f(unsigned short u){
  union { unsigned u; float f; } c; c.u = ((unsigned)u) << 16;
  return c.f;
}
__device__ __forceinline__ unsigned pack2(float a, float b){
  return (unsigned)f2b(a) | ((unsigned)f2b(b) << 16);
}

// ws layout (bytes) — total end 45,482,496 (< 45,744,128 proven in round 1)
#define OFF_WQKV 0ull            // 12*768*256  bf16 = 4,718,592
#define OFF_WO   4718592ull      // 12*256*256  bf16 = 1,572,864
#define OFF_L1   6291456ull      // 12*1024*256 bf16 = 6,291,456
#define OFF_L2   12582912ull     // 12*256*1024 bf16 = 6,291,456
#define OFF_SRC  18874368ull     // 128*256 f32 = 131,072
#define OFF_CC   19005440ull     // 12*128*256 bf16 = 786,432
#define OFF_KV   19791872ull     // 128*12*4*16*128 bf16 = 25,165,824
#define OFF_ZBUFB 44957696ull    // Wo partials [32][256][16] bf16 = 262,144
#define OFF_FLAGS 45219840ull    // 512 B
#define OFF_Z2B16 45220352ull    // lin2 partials [32][256][16] bf16 = 262,144

// ---------------- weight f32 -> bf16 conversion --------------------------
__global__ void k_conv(const float* __restrict__ wqkv, const float* __restrict__ wo,
                       const float* __restrict__ l1, const float* __restrict__ l2,
                       unsigned short* __restrict__ dst){
  const long long n0 = 12LL*768*256;
  const long long n1 = n0 + 12LL*256*256;
  const long long n2 = n1 + 12LL*1024*256;
  const long long n3 = n2 + 12LL*256*1024;
  for (long long idx = (long long)blockIdx.x*256 + threadIdx.x; idx < n3;
       idx += (long long)gridDim.x*256){
    float v;
    if (idx < n0) v = wqkv[idx];
    else if (idx < n1) v = wo[idx - n0];
    else if (idx < n2) v = l1[idx - n1];
    else v = l2[idx - n2];
    dst[idx] = f2b(v);
  }
}

// ---------------- src = vec @ tok_W.T + tok_b ----------------------------
__global__ void k_src(const float* __restrict__ U_real, const float* __restrict__ U_imag,
                      const float* __restrict__ tok_W, const float* __restrict__ tok_b,
                      float* __restrict__ src){
  int b = blockIdx.x, n = threadIdx.x;
  const float* w = tok_W + n*128;
  const float* ur = U_real + b*64;
  const float* ui = U_imag + b*64;
  float acc = tok_b[n];
  #pragma unroll 8
  for (int k = 0; k < 64; ++k) acc += w[k]*ur[k];
  #pragma unroll 8
  for (int k = 0; k < 64; ++k) acc += w[64+k]*ui[k];
  src[b*256+n] = acc;
}

// ------- cross-attn constant: cc[l][b] = Wo_ca @ (Wv_ca@src_b + bv) + bo --
__global__ void k_cc(const float* __restrict__ caW, const float* __restrict__ cab,
                     const float* __restrict__ caWo, const float* __restrict__ cabo,
                     const float* __restrict__ src, unsigned short* __restrict__ cc){
  int l = blockIdx.x >> 7, b = blockIdx.x & 127, t = threadIdx.x;
  __shared__ float v[256];
  const float* s = src + b*256;
  {
    const float* w = caW + ((long long)l*768 + 512 + t)*256;
    float a = cab[l*768 + 512 + t];
    #pragma unroll 8
    for (int k = 0; k < 256; ++k) a += w[k]*s[k];
    v[t] = a;
  }
  __syncthreads();
  {
    const float* w = caWo + ((long long)l*256 + t)*256;
    float a = cabo[l*256 + t];
    #pragma unroll 8
    for (int k = 0; k < 256; ++k) a += w[k]*v[k];
    cc[((long long)l*128 + b)*256 + t] = f2b(a);
  }
}

// ---------------- main decode kernel -------------------------------------
// Fence-free: data via agent relaxed atomics; barrier drains vmcnt(0) per
// wave before s_barrier, so stores are globally performed before the flag.
#define PUBWAIT(TYPE) do{                                                    \
  __syncthreads();                                                           \
  if (tid == 0)                                                              \
    __hip_atomic_store(flags + (TYPE)*32 + c*4 + s, seq,                     \
        __ATOMIC_RELAXED, __HIP_MEMORY_SCOPE_AGENT);                         \
  if (tid < 3){                                                              \
    int so = tid + (tid >= s ? 1 : 0);                                       \
    const int* fp = flags + (TYPE)*32 + c*4 + so;                            \
    while (__hip_atomic_load(fp, __ATOMIC_RELAXED,                           \
        __HIP_MEMORY_SCOPE_AGENT) < seq)                                     \
      __builtin_amdgcn_s_sleep(2);                                           \
  }                                                                          \
  __syncthreads();                                                           \
}while(0)

__global__ __launch_bounds__(512, 1) void k_main(
  const unsigned short* __restrict__ wqkv,   // [12][768][256] bf16
  const unsigned short* __restrict__ wo,     // [12][256][256]
  const unsigned short* __restrict__ wl1,    // [12][1024][256]
  const unsigned short* __restrict__ wl2,    // [12][256][1024]
  const float* __restrict__ bqkv, const float* __restrict__ bo_,
  const float* __restrict__ bl1,  const float* __restrict__ bl2,
  const float* __restrict__ g1, const float* __restrict__ be1,
  const float* __restrict__ g2, const float* __restrict__ be2,
  const float* __restrict__ g3, const float* __restrict__ be3,
  const unsigned short* __restrict__ cc,     // [12][128][256] bf16
  const float* __restrict__ src,             // [128][256]
  const float* __restrict__ pos,             // [17][256]
  const float* __restrict__ outW,            // [4][256]
  const float* __restrict__ outb,
  const float* __restrict__ plow, const float* __restrict__ phigh,
  unsigned short* __restrict__ kvc,          // [128][12][4][16][128] bf16 (k|v)
  unsigned int* __restrict__ zbuf,           // [32][256][8] u32 (2 rows/word)
  unsigned int* __restrict__ z2buf,          // [32][256][8] u32
  int* __restrict__ flags,                   // [2][8][4] (+pad)
  float* __restrict__ out)                   // [128][16][4]
{
  __shared__ float xf[16][260];            // running x (residual source)
  __shared__ float yf[16][260];            // y (post-LN2, FFN residual)
  __shared__ unsigned short xb[16][264];   // bf16 A-operand (x / y)
  __shared__ unsigned short hs[16][264];   // relu(lin1) slice bf16
  __shared__ unsigned short qs[16][72];    // q slice (head s)
  __shared__ unsigned short os[16][72];    // attn out slice (head s)

  const int tid  = threadIdx.x;
  const int w    = tid >> 6, lane = tid & 63;
  const int c    = blockIdx.x & 7;    // chain
  const int s    = blockIdx.x >> 3;   // slice / head
  const int mrow = lane & 15, kgrp = lane >> 4;

  // init: x = src + pos[0]
  {
    int row = tid >> 5, c8 = (tid & 31) * 8;
    const float* sp = src + (c*16 + row)*256 + c8;
    const float* pp = pos + c8;
    #pragma unroll
    for (int k = 0; k < 8; ++k){
      float v = sp[k] + pp[k];
      xf[row][c8+k] = v;
      xb[row][c8+k] = f2b(v);
    }
  }
  __syncthreads();

  for (int i = 0; i < 16; ++i){
    for (int l = 0; l < 12; ++l){
      const int seq = i*12 + l + 1;
      // ===== A1: QKV (head s) — 12 N-tiles over 8 waves =====
      {
        short8 a[8];
        #pragma unroll
        for (int kc = 0; kc < 8; ++kc)
          a[kc] = *(const short8*)&xb[mrow][kc*32 + kgrp*8];
        const unsigned short* wl = wqkv + (size_t)l*768*256;
        for (int t = w; t < 12; t += 8){
          int p = t >> 2, tt = t & 3;
          int n_l = tt*16 + mrow;                 // 0..63 within head slice
          const unsigned short* wp = wl + (size_t)(p*256 + s*64 + n_l)*256 + kgrp*8;
          f32x4 acc = {0,0,0,0};
          #pragma unroll
          for (int kc = 0; kc < 8; ++kc){
            short8 b0 = *(const short8*)(wp + kc*32);
            acc = __builtin_amdgcn_mfma_f32_16x16x32_bf16(a[kc], b0, acc, 0,0,0);
          }
          float bias = bqkv[l*768 + p*256 + s*64 + n_l];
          #pragma unroll
          for (int r = 0; r < 4; ++r){
            int br = kgrp*4 + r;
            float v = acc[r] + bias;
            if (p == 0){
              qs[br][n_l] = f2b(v);
            } else {
              size_t kb = ((((size_t)(c*16+br)*12 + l)*4 + s)*16 + i)*128;
              kvc[kb + (p == 2 ? 64 : 0) + n_l] = f2b(v);
            }
          }
        }
      }
      __syncthreads();
      // ===== A2: attention (head s) — 8 waves x 2 rows, 32 lanes/row =====
      {
        int row = w*2 + (lane >> 5);
        int lid = lane & 31;
        float q0 = b2f(qs[row][lid*2]), q1 = b2f(qs[row][lid*2+1]);
        const unsigned short* base =
            kvc + ((((size_t)(c*16+row)*12 + l)*4 + s)*16)*128 + lid*2;
        float sv[16];
        #pragma unroll
        for (int j = 0; j < 16; ++j){
          if (j <= i){
            const unsigned short* kp = base + j*128;
            float p = q0*b2f(kp[0]) + q1*b2f(kp[1]);
            p += __shfl_xor(p, 1);
            p += __shfl_xor(p, 2);
            p += __shfl_xor(p, 4);
            p += __shfl_xor(p, 8);
            p += __shfl_xor(p, 16);
            sv[j] = p * 0.125f;                 // 1/sqrt(64)
          } else sv[j] = -1e30f;
        }
        float mx = sv[0];
        #pragma unroll
        for (int j = 1; j < 16; ++j) mx = fmaxf(mx, sv[j]);
        float den = 0.f, e[16];
        #pragma unroll
        for (int j = 0; j < 16; ++j){ e[j] = __expf(sv[j]-mx); den += e[j]; }
        float rd = 1.f/den;
        float o0 = 0.f, o1 = 0.f;
        #pragma unroll
        for (int j = 0; j < 16; ++j){
          if (j <= i){
            const unsigned short* vp = base + j*128 + 64;
            o0 += e[j]*b2f(vp[0]);
            o1 += e[j]*b2f(vp[1]);
          }
        }
        os[row][lid*2]   = f2b(o0*rd);
        os[row][lid*2+1] = f2b(o1*rd);
      }
      __syncthreads();
      // ===== A3: Wo K-split partial (full N=256, K=64) -> zbuf atomics =====
      {
        short8 a2[2];
        #pragma unroll
        for (int kc = 0; kc < 2; ++kc)
          a2[kc] = *(const short8*)&os[mrow][kc*32 + kgrp*8];
        #pragma unroll
        for (int u = 0; u < 2; ++u){
          int n_g = (w*2+u)*16 + mrow;
          const unsigned short* wp = wo + (size_t)l*65536 + (size_t)n_g*256 + s*64 + kgrp*8;
          f32x4 acc = {0,0,0,0};
          #pragma unroll
          for (int kc = 0; kc < 2; ++kc){
            short8 b0 = *(const short8*)(wp + kc*32);
            acc = __builtin_amdgcn_mfma_f32_16x16x32_bf16(a2[kc], b0, acc, 0,0,0);
          }
          unsigned int* bp = zbuf + ((size_t)(c*4+s)*256 + n_g)*8 + kgrp*2;
          __hip_atomic_store(bp+0, pack2(acc[0], acc[1]),
              __ATOMIC_RELAXED, __HIP_MEMORY_SCOPE_AGENT);
          __hip_atomic_store(bp+1, pack2(acc[2], acc[3]),
              __ATOMIC_RELAXED, __HIP_MEMORY_SCOPE_AGENT);
        }
      }
      PUBWAIT(0);
      // ===== A4: sum partials + bias + residual -> LN1 + cc + LN2 =====
      {
        int row = w*2 + (lane >> 5), c8 = (lane & 31)*8;
        int half = (row & 1)*16, ridx = row >> 1;
        float t[8];
        #pragma unroll
        for (int k = 0; k < 8; ++k) t[k] = bo_[l*256 + c8 + k] + xf[row][c8+k];
        #pragma unroll
        for (int ss = 0; ss < 4; ++ss){
          const unsigned int* bp = zbuf + (size_t)(c*4+ss)*256*8 + ridx;
          #pragma unroll
          for (int k = 0; k < 8; ++k){
            unsigned int v = __hip_atomic_load(bp + (size_t)(c8+k)*8,
                __ATOMIC_RELAXED, __HIP_MEMORY_SCOPE_AGENT);
            t[k] += b2f((unsigned short)(v >> half));
          }
        }
        float sm = 0, sq = 0;
        #pragma unroll
        for (int k = 0; k < 8; ++k){ sm += t[k]; sq += t[k]*t[k]; }
        sm += __shfl_xor(sm,1);  sq += __shfl_xor(sq,1);
        sm += __shfl_xor(sm,2);  sq += __shfl_xor(sq,2);
        sm += __shfl_xor(sm,4);  sq += __shfl_xor(sq,4);
        sm += __shfl_xor(sm,8);  sq += __shfl_xor(sq,8);
        sm += __shfl_xor(sm,16); sq += __shfl_xor(sq,16);
        float mean = sm*(1.f/256), var = sq*(1.f/256) - mean*mean;
        float rs = rsqrtf(var + EPS_);
        const float* g1p = g1 + l*256 + c8;
        const float* b1p = be1 + l*256 + c8;
        const unsigned short* ccp = cc + ((size_t)l*128 + c*16 + row)*256 + c8;
        #pragma unroll
        for (int k = 0; k < 8; ++k)
          t[k] = (t[k]-mean)*rs*g1p[k] + b1p[k] + b2f(ccp[k]);
        sm = 0; sq = 0;
        #pragma unroll
        for (int k = 0; k < 8; ++k){ sm += t[k]; sq += t[k]*t[k]; }
        sm += __shfl_xor(sm,1);  sq += __shfl_xor(sq,1);
        sm += __shfl_xor(sm,2);  sq += __shfl_xor(sq,2);
        sm += __shfl_xor(sm,4);  sq += __shfl_xor(sq,4);
        sm += __shfl_xor(sm,8);  sq += __shfl_xor(sq,8);
        sm += __shfl_xor(sm,16); sq += __shfl_xor(sq,16);
        mean = sm*(1.f/256); var = sq*(1.f/256) - mean*mean;
        rs = rsqrtf(var + EPS_);
        const float* g2p = g2 + l*256 + c8;
        const float* b2p = be2 + l*256 + c8;
        #pragma unroll
        for (int k = 0; k < 8; ++k){
          float y = (t[k]-mean)*rs*g2p[k] + b2p[k];
          yf[row][c8+k] = y;
          xb[row][c8+k] = f2b(y);
        }
      }
      __syncthreads();
      // ===== B1: lin1 N-slice (s*256 .. +256) + relu -> hs =====
      {
        short8 a[8];
        #pragma unroll
        for (int kc = 0; kc < 8; ++kc)
          a[kc] = *(const short8*)&xb[mrow][kc*32 + kgrp*8];
        const unsigned short* wl = wl1 + (size_t)l*262144;
        #pragma unroll
        for (int u = 0; u < 2; ++u){
          int n_sl = (w*2+u)*16 + mrow;           // 0..255 within slice
          const unsigned short* wp = wl + (size_t)(s*256 + n_sl)*256 + kgrp*8;
          f32x4 acc = {0,0,0,0};
          #pragma unroll
          for (int kc = 0; kc < 8; ++kc){
            short8 b0 = *(const short8*)(wp + kc*32);
            acc = __builtin_amdgcn_mfma_f32_16x16x32_bf16(a[kc], b0, acc, 0,0,0);
          }
          float bias = bl1[l*1024 + s*256 + n_sl];
          #pragma unroll
          for (int r = 0; r < 4; ++r){
            float h = acc[r] + bias;
            hs[kgrp*4 + r][n_sl] = f2b(h > 0.f ? h : 0.f);
          }
        }
      }
      __syncthreads();
      // ===== B2: lin2 K-split partial -> z2buf atomics =====
      {
        short8 ah[8];
        #pragma unroll
        for (int kc = 0; kc < 8; ++kc)
          ah[kc] = *(const short8*)&hs[mrow][kc*32 + kgrp*8];
        #pragma unroll
        for (int u = 0; u < 2; ++u){
          int n_g = (w*2+u)*16 + mrow;
          const unsigned short* wp = wl2 + (size_t)l*262144 + (size_t)n_g*1024 + s*256 + kgrp*8;
          f32x4 acc = {0,0,0,0};
          #pragma unroll
          for (int kc = 0; kc < 8; ++kc){
            short8 b0 = *(const short8*)(wp + kc*32);
            acc = __builtin_amdgcn_mfma_f32_16x16x32_bf16(ah[kc], b0, acc, 0,0,0);
          }
          unsigned int* bp = z2buf + ((size_t)(c*4+s)*256 + n_g)*8 + kgrp*2;
          __hip_atomic_store(bp+0, pack2(acc[0], acc[1]),
              __ATOMIC_RELAXED, __HIP_MEMORY_SCOPE_AGENT);
          __hip_atomic_store(bp+1, pack2(acc[2], acc[3]),
              __ATOMIC_RELAXED, __HIP_MEMORY_SCOPE_AGENT);
        }
      }
      PUBWAIT(1);
      // ===== B3: sum partials + bias + residual -> LN3 (+ head @ l==11) =====
      {
        int row = w*2 + (lane >> 5), c8 = (lane & 31)*8;
        int half = (row & 1)*16, ridx = row >> 1;
        float t[8];
        #pragma unroll
        for (int k = 0; k < 8; ++k) t[k] = bl2[l*256 + c8 + k] + yf[row][c8+k];
        #pragma unroll
        for (int ss = 0; ss < 4; ++ss){
          const unsigned int* bp = z2buf + (size_t)(c*4+ss)*256*8 + ridx;
          #pragma unroll
          for (int k = 0; k < 8; ++k){
            unsigned int v = __hip_atomic_load(bp + (size_t)(c8+k)*8,
                __ATOMIC_RELAXED, __HIP_MEMORY_SCOPE_AGENT);
            t[k] += b2f((unsigned short)(v >> half));
          }
        }
        float sm = 0, sq = 0;
        #pragma unroll
        for (int k = 0; k < 8; ++k){ sm += t[k]; sq += t[k]*t[k]; }
        sm += __shfl_xor(sm,1);  sq += __shfl_xor(sq,1);
        sm += __shfl_xor(sm,2);  sq += __shfl_xor(sq,2);
        sm += __shfl_xor(sm,4);  sq += __shfl_xor(sq,4);
        sm += __shfl_xor(sm,8);  sq += __shfl_xor(sq,8);
        sm += __shfl_xor(sm,16); sq += __shfl_xor(sq,16);
        float mean = sm*(1.f/256), var = sq*(1.f/256) - mean*mean;
        float rs = rsqrtf(var + EPS_);
        const float* g3p = g3 + l*256 + c8;
        const float* b3p = be3 + l*256 + c8;
        float xn[8];
        #pragma unroll
        for (int k = 0; k < 8; ++k)
          xn[k] = (t[k]-mean)*rs*g3p[k] + b3p[k];
        if (l == 11){
          if (s == 0){
            float pr[4];
            #pragma unroll
            for (int p = 0; p < 4; ++p){
              float a = 0.f;
              #pragma unroll
              for (int k = 0; k < 8; ++k) a += xn[k]*outW[p*256 + c8 + k];
              a += __shfl_xor(a,1); a += __shfl_xor(a,2);
              a += __shfl_xor(a,4); a += __shfl_xor(a,8);
              a += __shfl_xor(a,16);
              pr[p] = a;
            }
            if ((lane & 31) == 0){
              int g = c*16 + row;
              #pragma unroll
              for (int p = 0; p < 4; ++p){
                float tt = pr[p] + outb[p];
                float sg = 1.f/(1.f + __expf(-tt));
                out[((size_t)g*16 + i)*4 + p] = plow[p] + (phigh[p]-plow[p])*sg;
              }
            }
          }
          if (i < 15){
            const float* pp = pos + (i+1)*256 + c8;
            #pragma unroll
            for (int k = 0; k < 8; ++k) xn[k] += pp[k];
          }
        }
        #pragma unroll
        for (int k = 0; k < 8; ++k){
          xf[row][c8+k] = xn[k];
          xb[row][c8+k] = f2b(xn[k]);
        }
      }
      __syncthreads();
    }
  }
}

extern "C" void kernel_launch(void* const* d_in, const int* in_sizes, int n_in,
                              void* d_out, int out_size, void* d_ws, size_t ws_size,
                              hipStream_t stream) {
  const float* U_real = (const float*)d_in[0];
  const float* U_imag = (const float*)d_in[1];
  const float* tok_W  = (const float*)d_in[2];
  const float* tok_b  = (const float*)d_in[3];
  const float* pos    = (const float*)d_in[4];
  const float* saW    = (const float*)d_in[5];
  const float* sab    = (const float*)d_in[6];
  const float* saWo   = (const float*)d_in[7];
  const float* sabo   = (const float*)d_in[8];
  const float* caW    = (const float*)d_in[9];
  const float* cab    = (const float*)d_in[10];
  const float* caWo   = (const float*)d_in[11];
  const float* cabo   = (const float*)d_in[12];
  const float* l1W    = (const float*)d_in[13];
  const float* l1b    = (const float*)d_in[14];
  const float* l2W    = (const float*)d_in[15];
  const float* l2b    = (const float*)d_in[16];
  const float* g1     = (const float*)d_in[17];
  const float* be1    = (const float*)d_in[18];
  const float* g2     = (const float*)d_in[19];
  const float* be2    = (const float*)d_in[20];
  const float* g3     = (const float*)d_in[21];
  const float* be3    = (const float*)d_in[22];
  const float* outW   = (const float*)d_in[23];
  const float* outb   = (const float*)d_in[24];
  const float* plow   = (const float*)d_in[25];
  const float* phigh  = (const float*)d_in[26];

  char* ws = (char*)d_ws;
  unsigned short* wb    = (unsigned short*)(ws + OFF_WQKV);
  float* srcb           = (float*)(ws + OFF_SRC);
  unsigned short* ccb   = (unsigned short*)(ws + OFF_CC);
  unsigned short* kvc   = (unsigned short*)(ws + OFF_KV);
  unsigned int* zbuf    = (unsigned int*)(ws + OFF_ZBUFB);
  unsigned int* z2buf   = (unsigned int*)(ws + OFF_Z2B16);
  int* flags            = (int*)(ws + OFF_FLAGS);

  (void)hipMemsetAsync(ws + OFF_FLAGS, 0, 512, stream);
  k_conv<<<dim3(4608), dim3(256), 0, stream>>>(saW, saWo, l1W, l2W, wb);
  k_src<<<dim3(128), dim3(256), 0, stream>>>(U_real, U_imag, tok_W, tok_b, srcb);
  k_cc<<<dim3(1536), dim3(256), 0, stream>>>(caW, cab, caWo, cabo, srcb, ccb);
  k_main<<<dim3(32), dim3(512), 0, stream>>>(
      wb,
      (unsigned short*)(ws + OFF_WO),
      (unsigned short*)(ws + OFF_L1),
      (unsigned short*)(ws + OFF_L2),
      sab, sabo, l1b, l2b,
      g1, be1, g2, be2, g3, be3,
      ccb, srcb, pos, outW, outb, plow, phigh,
      kvc, zbuf, z2buf, flags, (float*)d_out);
}